// Round 2
// baseline (3513.521 us; speedup 1.0000x reference)
//
#include <hip/hip_runtime.h>

// RNN with feedback projection, MI355X persistent-kernel implementation, R4.
// B=256, T=200, D_IN=512, UNITS=1024, PROJ=512.
//
// pre = [h | sigmoid(p) | x_t] @ [Wr; Wf; Wk] + bias  (K=2048)
// h   = tanh(pre) ;  p = h @ Wp + pb                  (K=1024)
//
// 256 blocks = 8 batch-groups (32 rows) x 32 column-blocks, cooperative launch.
//
// R3 post-mortem: XCD-local plain-store/plain-load+buffer_inv data path gave
// absmax 4.0 (completed => flags worked, data visibility broke). R4 bisects:
// ALL cross-block data+flags via R2-proven agent-scope relaxed atomics
// (LLC-coherent, no cache maintenance), keeping R3's protocol-level wins:
//  1. Flag-array barrier: producer stores one monotonic counter (t+1) to its
//     slot; consumers poll all 32 flags with ONE coalesced load + __all.
//     Removes R2's fetch_add + generation-bump two-hop chain.
//  2. Single-wave publisher: wave 0 stores h/sigp, one s_waitcnt(0) drain is
//     the release, then the flag store.
//  3. Per-wave polling, no barrier handoff: each consumer wave polls the flag
//     line itself; wave 3 (x-only, needs no coherence) skips the loop-top
//     wait and overlaps its HBM x-loads + MFMAs with the others' polls.
//  4. out stores after the flag store (never read back -> off the drain path).
// All LDS (red/hs/ps) read-write pairs remain separated by __syncthreads.

#define T_   200
#define DIN  512
#define U_   1024
#define P_   512

typedef _Float16 f16x8 __attribute__((ext_vector_type(8)));
typedef float    f32x4 __attribute__((ext_vector_type(4)));
typedef unsigned long long u64;

#define WPACK_ELEMS    2097152
#define WPPACK_ELEMS   524288
#define ABUFINIT_ELEMS 393216
#define WPACK_BYTES    4194304u
#define WPPACK_BYTES   1048576u
#define ABUF_BYTES     1572864u
#define AB_GROUP       98304      // f16 elems per group (2 bufs)
#define AB_BUF         49152      // f16 elems per buffer: [rt 2][kt 48][lane 64][j 8]

// bars layout (unsigned):
//   [0..255]    barA[group][cb]   (h ready, value = t+1)
//   [256..511]  barB[group][cb]   (sigp ready, value = t+1)
#define BARS_WORDS 512

#define MFMA16(a, b, c) __builtin_amdgcn_mfma_f32_16x16x32_f16((a), (b), (c), 0, 0, 0)

__global__ __launch_bounds__(256) void prep_kernel(
    const float* __restrict__ krn, const float* __restrict__ rk,
    const float* __restrict__ fk, const float* __restrict__ pk,
    _Float16* __restrict__ Wpack, _Float16* __restrict__ Wppack,
    _Float16* __restrict__ Abuf, unsigned* __restrict__ bars)
{
  int n = blockIdx.x * 256 + threadIdx.x;
  if (blockIdx.x == 0) {
    for (int i = threadIdx.x; i < BARS_WORDS; i += 256) bars[i] = 0u;
  }

  if (n < WPACK_ELEMS) {
    // [cb 32][w 4][kt 16][ct 2][lane 64][j 8]; k = w*512+kt*32+((lane>>4)<<3)+j
    int j = n & 7, lane = (n >> 3) & 63, ct = (n >> 9) & 1;
    int kt = (n >> 10) & 15, w = (n >> 14) & 3, cb = n >> 16;
    int k   = w * 512 + kt * 32 + ((lane >> 4) << 3) + j;
    int col = cb * 32 + ct * 16 + (lane & 15);
    float v;
    if (k < 1024)       v = rk[(size_t)k * 1024 + col];
    else if (k < 1536)  v = fk[(size_t)(k - 1024) * 1024 + col];
    else                v = krn[(size_t)(k - 1536) * 1024 + col];
    Wpack[n] = (_Float16)v;
    return;
  }
  n -= WPACK_ELEMS;
  if (n < WPPACK_ELEMS) {
    // [cb 32][w 4][kt 8][lane 64][j 8]; k = w*256+kt*32+((lane>>4)<<3)+j
    int j = n & 7, lane = (n >> 3) & 63, kt = (n >> 9) & 7;
    int w = (n >> 12) & 3, cb = n >> 14;
    int k   = w * 256 + kt * 32 + ((lane >> 4) << 3) + j;
    int col = cb * 16 + (lane & 15);
    Wppack[n] = (_Float16)pk[(size_t)k * 512 + col];
    return;
  }
  n -= WPPACK_ELEMS;
  if (n < ABUFINIT_ELEMS) {
    // buf0 init per group: kt<32 (h) -> 0 ; kt 32..47 (sigp) -> sigmoid(0)=0.5
    int g = n / AB_BUF;
    int q = n % AB_BUF;
    int kt = (q >> 9) % 48;
    Abuf[(size_t)g * AB_GROUP + q] = (_Float16)((kt < 32) ? 0.0f : 0.5f);
  }
}

// ---- LLC-coherent (agent-scope, relaxed, no cache maintenance) primitives ----
__device__ __forceinline__ f16x8 llc_load8(const _Float16* p) {
  u64 lo = __hip_atomic_load((const u64*)p,     __ATOMIC_RELAXED, __HIP_MEMORY_SCOPE_AGENT);
  u64 hi = __hip_atomic_load((const u64*)p + 1, __ATOMIC_RELAXED, __HIP_MEMORY_SCOPE_AGENT);
  union { u64 u[2]; f16x8 v; } c; c.u[0] = lo; c.u[1] = hi; return c.v;
}
__device__ __forceinline__ void llc_store16(_Float16* p, f16x8 v) {
  union { f16x8 v; u64 u[2]; } c; c.v = v;
  __hip_atomic_store((u64*)p,     c.u[0], __ATOMIC_RELAXED, __HIP_MEMORY_SCOPE_AGENT);
  __hip_atomic_store((u64*)p + 1, c.u[1], __ATOMIC_RELAXED, __HIP_MEMORY_SCOPE_AGENT);
}

// per-wave: wait until all 32 flags of this group reach tgt (monotonic, no reset)
__device__ __forceinline__ void group_wait(const unsigned* fl, int l, unsigned tgt) {
  const unsigned* p = fl + (l & 31);
  for (;;) {
    unsigned v = tgt;
    if (l < 32) v = __hip_atomic_load(p, __ATOMIC_RELAXED, __HIP_MEMORY_SCOPE_AGENT);
    if (__all((int)(v >= tgt))) break;
    __builtin_amdgcn_s_sleep(1);
  }
}

__global__ __launch_bounds__(256, 1) void rnn_main(
    const float* __restrict__ x, const float* __restrict__ bias,
    const float* __restrict__ pbias,
    const _Float16* __restrict__ Wpack, const _Float16* __restrict__ Wppack,
    _Float16* __restrict__ Abuf, unsigned* __restrict__ bars,
    float* __restrict__ out)
{
  __shared__ f32x4 red[4][4][64];      // 16 KiB cross-wave K-reduction
  __shared__ _Float16 hs[32][40];      // h tile staging (+8 pad)
  __shared__ _Float16 ps[32][24];      // sigp tile staging

  const int bid = blockIdx.x;
  const int g   = bid & 7;     // batch group (32 rows); bid%8 ~ XCD affinity
  const int cb  = bid >> 3;    // UNITS cols cb*32..+32, PROJ cols cb*16..+16
  const int tid = threadIdx.x;
  const int w   = tid >> 6;    // wave id = K-quarter
  const int l   = tid & 63;

  // register-resident weight fragments (fp16, MFMA B-operand layout)
  f16x8 wA[16][2];
  {
    const _Float16* wb = Wpack + (((size_t)cb * 4 + w) << 14);
#pragma unroll
    for (int kt = 0; kt < 16; ++kt)
#pragma unroll
      for (int ct = 0; ct < 2; ++ct)
        wA[kt][ct] = *(const f16x8*)(wb + (((kt * 2 + ct) * 64 + l) << 3));
  }
  f16x8 wP[8];
  {
    const _Float16* wb = Wppack + (((size_t)cb * 4 + w) << 12);
#pragma unroll
    for (int kt = 0; kt < 8; ++kt)
      wP[kt] = *(const f16x8*)(wb + ((kt * 64 + l) << 3));
  }

  const int rtA = w >> 1, ctA = w & 1;
  const float biasv = bias[cb * 32 + ctA * 16 + (l & 15)];
  const float pbv   = pbias[cb * 16 + (l & 15)];

  _Float16* abg  = Abuf + (size_t)g * AB_GROUP;
  unsigned* barA = bars + g * 32;
  unsigned* barB = bars + 256 + g * 32;

  // wave-3 x addressing: row = g*32 + rt*16 + (l&15), octet base col = (l>>4)*8
  const float* xrow0 = x + (size_t)(g * 32 + (l & 15)) * T_ * DIN;
  const float* xrow1 = x + (size_t)(g * 32 + 16 + (l & 15)) * T_ * DIN;
  const int xco = (l >> 4) << 3;

  for (int t = 0; t < T_; ++t) {
    const _Float16* acur = abg + (size_t)(t & 1) * AB_BUF;
    _Float16* anxt       = abg + (size_t)((t & 1) ^ 1) * AB_BUF;

    // ---- consumer-side wait: waves 0..2 poll sigp/h readiness (barB >= t).
    // barB[Y]=t transitively implies barA>=t (Y flags barB only after passing
    // its barA poll), so h(t-1) AND sigp(t-1) are LLC-visible. Wave 3 reads
    // only x -> skips the wait, overlapping its HBM loads with the polls.
    if (w < 3 && t > 0) group_wait(barB, l, (unsigned)t);

    // ============ phase A: pre = [h|sigp|x] @ Wcomb ; h = tanh(pre+bias) ============
    f32x4 a00 = {0.f,0.f,0.f,0.f}, a01 = a00, a10 = a00, a11 = a00;
    if (w < 3) {
      // waves 0,1: h (K 0..1023); wave 2: sigp (K 1024..1535) — LLC loads
#pragma unroll
      for (int kt = 0; kt < 16; ++kt) {
        const int ktg = w * 16 + kt;
        f16x8 fa0 = llc_load8(acur + (size_t)ktg * 512 + l * 8);
        f16x8 fa1 = llc_load8(acur + (size_t)(48 + ktg) * 512 + l * 8);
        a00 = MFMA16(fa0, wA[kt][0], a00);
        a01 = MFMA16(fa0, wA[kt][1], a01);
        a10 = MFMA16(fa1, wA[kt][0], a10);
        a11 = MFMA16(fa1, wA[kt][1], a11);
      }
    } else {
      // wave 3: x (K 1536..2047) — ordinary cached fp32 loads + cvt
      const float* xp0 = xrow0 + (size_t)t * DIN + xco;
      const float* xp1 = xrow1 + (size_t)t * DIN + xco;
#pragma unroll
      for (int kt = 0; kt < 16; ++kt) {
        float4 u0 = *(const float4*)(xp0 + kt * 32);
        float4 u1 = *(const float4*)(xp0 + kt * 32 + 4);
        float4 v0 = *(const float4*)(xp1 + kt * 32);
        float4 v1 = *(const float4*)(xp1 + kt * 32 + 4);
        f16x8 fa0, fa1;
        fa0[0]=(_Float16)u0.x; fa0[1]=(_Float16)u0.y; fa0[2]=(_Float16)u0.z; fa0[3]=(_Float16)u0.w;
        fa0[4]=(_Float16)u1.x; fa0[5]=(_Float16)u1.y; fa0[6]=(_Float16)u1.z; fa0[7]=(_Float16)u1.w;
        fa1[0]=(_Float16)v0.x; fa1[1]=(_Float16)v0.y; fa1[2]=(_Float16)v0.z; fa1[3]=(_Float16)v0.w;
        fa1[4]=(_Float16)v1.x; fa1[5]=(_Float16)v1.y; fa1[6]=(_Float16)v1.z; fa1[7]=(_Float16)v1.w;
        a00 = MFMA16(fa0, wA[kt][0], a00);
        a01 = MFMA16(fa0, wA[kt][1], a01);
        a10 = MFMA16(fa1, wA[kt][0], a10);
        a11 = MFMA16(fa1, wA[kt][1], a11);
      }
    }
    red[w][0][l] = a00; red[w][1][l] = a01; red[w][2][l] = a10; red[w][3][l] = a11;
    __syncthreads();                                     // S1
    {
      // wave w owns tile (rtA, ctA): reduce K-partials, tanh, stage in LDS
      f32x4 s = red[0][w][l];
      s += red[1][w][l]; s += red[2][w][l]; s += red[3][w][l];
      const int c = ctA * 16 + (l & 15);
#pragma unroll
      for (int i = 0; i < 4; ++i) {
        const int r = rtA * 16 + ((l >> 4) << 2) + i;
        hs[r][c] = (_Float16)tanhf(s[i] + biasv);
      }
    }
    __syncthreads();                                     // S2
    // wave 0 publishes h (128 x 16B units, 2 per lane): store, drain, flag
    if (tid < 64) {
      const int row16 = l & 15, o = (l >> 4) & 3;
      f16x8 t0, t1;
#pragma unroll
      for (int jj = 0; jj < 8; ++jj) {
        t0[jj] = hs[row16][o * 8 + jj];
        t1[jj] = hs[16 + row16][o * 8 + jj];
      }
      const size_t so = (size_t)(((o << 4) | row16) * 8);
      llc_store16(anxt + (size_t)cb * 512 + so, t0);
      llc_store16(anxt + (size_t)(48 + cb) * 512 + so, t1);
      asm volatile("" ::: "memory");
      __builtin_amdgcn_s_waitcnt(0);            // h committed at LLC
      asm volatile("" ::: "memory");
      if (tid == 0)
        __hip_atomic_store(barA + cb, (unsigned)(t + 1),
                           __ATOMIC_RELAXED, __HIP_MEMORY_SCOPE_AGENT);
      asm volatile("" ::: "memory");
    }
    // ALL waves poll h readiness themselves (no barrier handoff)
    group_wait(barA, l, (unsigned)(t + 1));

    // ================= phase B: p = h @ Wp + pb ; sigp = sigmoid(p) =================
    f32x4 b0 = {0.f,0.f,0.f,0.f}, b1 = b0;
#pragma unroll
    for (int kt = 0; kt < 8; ++kt) {
      const int ktg = w * 8 + kt;
      f16x8 h0 = llc_load8(anxt + (size_t)ktg * 512 + l * 8);
      f16x8 h1 = llc_load8(anxt + (size_t)(48 + ktg) * 512 + l * 8);
      b0 = MFMA16(h0, wP[kt], b0);
      b1 = MFMA16(h1, wP[kt], b1);
    }
    red[w][0][l] = b0; red[w][1][l] = b1;
    __syncthreads();                                     // S3
    f32x4 pv = {0.f,0.f,0.f,0.f};
    const bool have_p = (w < 2);
    if (have_p) {
      // wave w owns row-tile w: reduce, +pb; sigmoid -> LDS; keep p in regs
      f32x4 s = red[0][w][l];
      s += red[1][w][l]; s += red[2][w][l]; s += red[3][w][l];
#pragma unroll
      for (int i = 0; i < 4; ++i) {
        const int grow = w * 16 + ((l >> 4) << 2) + i;
        float p = s[i] + pbv;
        pv[i] = p;
        ps[grow][l & 15] = (_Float16)(1.0f / (1.0f + __expf(-p)));
      }
    }
    __syncthreads();                                     // S4
    // wave 0 publishes sigp (64 x 16B units): store, drain, flag
    if (tid < 64) {
      const int rt = l >> 5, u2 = l & 31;
      const int row16 = u2 & 15, o = u2 >> 4;
      const int kt2 = 32 + (cb >> 1);
      const int oo  = ((cb & 1) << 1) | o;
      f16x8 tp;
#pragma unroll
      for (int jj = 0; jj < 8; ++jj) tp[jj] = ps[rt * 16 + row16][o * 8 + jj];
      llc_store16(anxt + (size_t)(rt * 48 + kt2) * 512 + (size_t)(((oo << 4) | row16) * 8), tp);
      asm volatile("" ::: "memory");
      __builtin_amdgcn_s_waitcnt(0);            // sigp committed at LLC
      asm volatile("" ::: "memory");
      if (tid == 0)
        __hip_atomic_store(barB + cb, (unsigned)(t + 1),
                           __ATOMIC_RELAXED, __HIP_MEMORY_SCOPE_AGENT);
      asm volatile("" ::: "memory");
    }
    // out stores AFTER the flag: never read back, off the drain path
    if (have_p) {
      const int pcol = cb * 16 + (l & 15);
#pragma unroll
      for (int i = 0; i < 4; ++i) {
        const int grow = w * 16 + ((l >> 4) << 2) + i;
        out[((size_t)(g * 32 + grow) * T_ + t) * P_ + pcol] = pv[i];
      }
    }
    // next iteration's loop-top poll (barB >= t+1) is the consumer-side wait
  }
}

extern "C" void kernel_launch(void* const* d_in, const int* in_sizes, int n_in,
                              void* d_out, int out_size, void* d_ws, size_t ws_size,
                              hipStream_t stream)
{
  const float* x    = (const float*)d_in[0];
  const float* krn  = (const float*)d_in[1];
  const float* rk   = (const float*)d_in[2];
  const float* fk   = (const float*)d_in[3];
  const float* pk   = (const float*)d_in[4];
  const float* bias = (const float*)d_in[5];
  const float* pb   = (const float*)d_in[6];
  float* out = (float*)d_out;

  char* ws = (char*)d_ws;
  _Float16* Wpack  = (_Float16*)(ws);
  _Float16* Wppack = (_Float16*)(ws + WPACK_BYTES);
  _Float16* Abuf   = (_Float16*)(ws + WPACK_BYTES + WPPACK_BYTES);
  unsigned* bars   = (unsigned*)(ws + WPACK_BYTES + WPPACK_BYTES + ABUF_BYTES);
  // ws use: 4 MiB + 1 MiB + 1.5 MiB + 2 KiB

  // pack weights, init step-0 activation buffer, zero barriers (every launch:
  // harness re-poisons ws to 0xAA before each timed call)
  hipLaunchKernelGGL(prep_kernel, dim3(11776), dim3(256), 0, stream,
                     krn, rk, fk, pk, Wpack, Wppack, Abuf, bars);

  void* args[] = { (void*)&x, (void*)&bias, (void*)&pb, (void*)&Wpack, (void*)&Wppack,
                   (void*)&Abuf, (void*)&bars, (void*)&out };
  hipLaunchCooperativeKernel((void*)rnn_main, dim3(256), dim3(256), args, 0, stream);
}

// Round 5
// 3322.238 us; speedup vs baseline: 1.0576x; 1.0576x over previous
//
#include <hip/hip_runtime.h>

// RNN with feedback projection, MI355X persistent-kernel implementation, R7.
// B=256, T=200, D_IN=512, UNITS=1024, PROJ=512.
//
// pre = [h | sigmoid(p) | x_t] @ [Wr; Wf; Wk] + bias  (K=2048)
// h   = tanh(pre) ;  p = h @ Wp + pb                  (K=1024)
//
// 256 blocks = 8 batch-groups (32 rows) x 32 column-blocks, cooperative launch.
//
// Empirical law after R3/R5/R6 (all absmax-identical failures): agent-scope
// relaxed loads are only reliably FRESH in the exact interleaved
// load->consume pattern of R2/R4; batch-hoisting them (inline asm OR
// compiler atomics + sched_barrier) deterministically reads stale data.
// The load pattern is therefore FROZEN as in R4.
//
// Live model: R4's 17us/step == 96 serialized 8B LLC RTTs per wave per step
// (each llc_load8 = 2 u64 loads x ~170ns; barrier hops are the +-2us that
// R4's null result showed). R7 shortens the SERIAL CHAIN by re-partitioning:
// 1024 threads / 16 waves per block, each wave owns K/16 (was K/4):
//   waves 0-7: h (ktg = w*4+kt), 8-11: sigp (same formula), 12-15: x.
// Per-wave chain: 16 u64 (A) + 8 u64 (B) = 24 RTTs ~= 4us, vs 96.
// Packed weight layouts slice cleanly into sixteenths (prep unchanged).
// Publish/flag/poll protocol verbatim R4. red[] grows to 16 partials (64KiB
// LDS). Poll sleep 1->4 (3.5x more spinning waves). ~110 VGPR < 128 cap.

#define T_   200
#define DIN  512
#define U_   1024
#define P_   512

typedef _Float16 f16x8 __attribute__((ext_vector_type(8)));
typedef float    f32x4 __attribute__((ext_vector_type(4)));
typedef unsigned long long u64;

#define WPACK_ELEMS    2097152
#define WPPACK_ELEMS   524288
#define ABUFINIT_ELEMS 393216
#define WPACK_BYTES    4194304u
#define WPPACK_BYTES   1048576u
#define ABUF_BYTES     1572864u
#define AB_GROUP       98304      // f16 elems per group (2 bufs)
#define AB_BUF         49152      // f16 elems per buffer: [rt 2][kt 48][lane 64][j 8]

// bars layout (unsigned):
//   [0..255]    barA[group][cb]   (h ready, value = t+1)
//   [256..511]  barB[group][cb]   (sigp ready, value = t+1)
#define BARS_WORDS 512

#define MFMA16(a, b, c) __builtin_amdgcn_mfma_f32_16x16x32_f16((a), (b), (c), 0, 0, 0)

__global__ __launch_bounds__(256) void prep_kernel(
    const float* __restrict__ krn, const float* __restrict__ rk,
    const float* __restrict__ fk, const float* __restrict__ pk,
    _Float16* __restrict__ Wpack, _Float16* __restrict__ Wppack,
    _Float16* __restrict__ Abuf, unsigned* __restrict__ bars)
{
  int n = blockIdx.x * 256 + threadIdx.x;
  if (blockIdx.x == 0) {
    for (int i = threadIdx.x; i < BARS_WORDS; i += 256) bars[i] = 0u;
  }

  if (n < WPACK_ELEMS) {
    // [cb 32][w 4][kt 16][ct 2][lane 64][j 8]; k = w*512+kt*32+((lane>>4)<<3)+j
    int j = n & 7, lane = (n >> 3) & 63, ct = (n >> 9) & 1;
    int kt = (n >> 10) & 15, w = (n >> 14) & 3, cb = n >> 16;
    int k   = w * 512 + kt * 32 + ((lane >> 4) << 3) + j;
    int col = cb * 32 + ct * 16 + (lane & 15);
    float v;
    if (k < 1024)       v = rk[(size_t)k * 1024 + col];
    else if (k < 1536)  v = fk[(size_t)(k - 1024) * 1024 + col];
    else                v = krn[(size_t)(k - 1536) * 1024 + col];
    Wpack[n] = (_Float16)v;
    return;
  }
  n -= WPACK_ELEMS;
  if (n < WPPACK_ELEMS) {
    // [cb 32][w 4][kt 8][lane 64][j 8]; k = w*256+kt*32+((lane>>4)<<3)+j
    int j = n & 7, lane = (n >> 3) & 63, kt = (n >> 9) & 7;
    int w = (n >> 12) & 3, cb = n >> 14;
    int k   = w * 256 + kt * 32 + ((lane >> 4) << 3) + j;
    int col = cb * 16 + (lane & 15);
    Wppack[n] = (_Float16)pk[(size_t)k * 512 + col];
    return;
  }
  n -= WPPACK_ELEMS;
  if (n < ABUFINIT_ELEMS) {
    // buf0 init per group: kt<32 (h) -> 0 ; kt 32..47 (sigp) -> sigmoid(0)=0.5
    int g = n / AB_BUF;
    int q = n % AB_BUF;
    int kt = (q >> 9) % 48;
    Abuf[(size_t)g * AB_GROUP + q] = (_Float16)((kt < 32) ? 0.0f : 0.5f);
  }
}

// ---- LLC-coherent (agent-scope, relaxed, no cache maintenance) primitives ----
__device__ __forceinline__ f16x8 llc_load8(const _Float16* p) {
  u64 lo = __hip_atomic_load((const u64*)p,     __ATOMIC_RELAXED, __HIP_MEMORY_SCOPE_AGENT);
  u64 hi = __hip_atomic_load((const u64*)p + 1, __ATOMIC_RELAXED, __HIP_MEMORY_SCOPE_AGENT);
  union { u64 u[2]; f16x8 v; } c; c.u[0] = lo; c.u[1] = hi; return c.v;
}
__device__ __forceinline__ void llc_store16(_Float16* p, f16x8 v) {
  union { f16x8 v; u64 u[2]; } c; c.v = v;
  __hip_atomic_store((u64*)p,     c.u[0], __ATOMIC_RELAXED, __HIP_MEMORY_SCOPE_AGENT);
  __hip_atomic_store((u64*)p + 1, c.u[1], __ATOMIC_RELAXED, __HIP_MEMORY_SCOPE_AGENT);
}

// per-wave: wait until all 32 flags of this group reach tgt (monotonic, no reset)
__device__ __forceinline__ void group_wait(const unsigned* fl, int l, unsigned tgt) {
  const unsigned* p = fl + (l & 31);
  for (;;) {
    unsigned v = tgt;
    if (l < 32) v = __hip_atomic_load(p, __ATOMIC_RELAXED, __HIP_MEMORY_SCOPE_AGENT);
    if (__all((int)(v >= tgt))) break;
    __builtin_amdgcn_s_sleep(4);
  }
}

__global__ __launch_bounds__(1024, 4) void rnn_main(
    const float* __restrict__ x, const float* __restrict__ bias,
    const float* __restrict__ pbias,
    const _Float16* __restrict__ Wpack, const _Float16* __restrict__ Wppack,
    _Float16* __restrict__ Abuf, unsigned* __restrict__ bars,
    float* __restrict__ out)
{
  __shared__ f32x4 red[16][4][64];     // 64 KiB cross-wave K-reduction (16 partials)
  __shared__ _Float16 hs[32][40];      // h tile staging (+8 pad)
  __shared__ _Float16 ps[32][24];      // sigp tile staging

  const int bid = blockIdx.x;
  const int g   = bid & 7;     // batch group (32 rows); bid%8 ~ XCD affinity
  const int cb  = bid >> 3;    // UNITS cols cb*32..+32, PROJ cols cb*16..+16
  const int tid = threadIdx.x;
  const int w   = tid >> 6;    // wave id = K-sixteenth
  const int l   = tid & 63;

  // register-resident weight fragments (fp16, MFMA B-operand layout)
  // wave w owns K in [w*128, w*128+128): 4 kt fragments of 32 for phase A
  f16x8 wA[4][2];
  {
    const _Float16* wb = Wpack + (((size_t)cb * 16 + w) << 12);
#pragma unroll
    for (int kt = 0; kt < 4; ++kt)
#pragma unroll
      for (int ct = 0; ct < 2; ++ct)
        wA[kt][ct] = *(const f16x8*)(wb + (((kt * 2 + ct) * 64 + l) << 3));
  }
  // phase B: wave w owns K in [w*64, w*64+64): 2 kt fragments
  f16x8 wP[2];
  {
    const _Float16* wb = Wppack + (((size_t)cb * 16 + w) << 10);
#pragma unroll
    for (int kt = 0; kt < 2; ++kt)
      wP[kt] = *(const f16x8*)(wb + ((kt * 64 + l) << 3));
  }

  // reduce-phase tile ownership (waves 0-3 for h; waves 0-1 for p)
  const int rtA = (w >> 1) & 1, ctA = w & 1;
  const float biasv = bias[cb * 32 + ctA * 16 + (l & 15)];
  const float pbv   = pbias[cb * 16 + (l & 15)];

  _Float16* abg  = Abuf + (size_t)g * AB_GROUP;
  unsigned* barA = bars + g * 32;
  unsigned* barB = bars + 256 + g * 32;

  // x-wave addressing (waves 12-15): row = g*32 + rt*16 + (l&15)
  const float* xrow0 = x + (size_t)(g * 32 + (l & 15)) * T_ * DIN;
  const float* xrow1 = x + (size_t)(g * 32 + 16 + (l & 15)) * T_ * DIN;
  const int xco = (l >> 4) << 3;

  for (int t = 0; t < T_; ++t) {
    const _Float16* acur = abg + (size_t)(t & 1) * AB_BUF;
    _Float16* anxt       = abg + (size_t)((t & 1) ^ 1) * AB_BUF;

    // ---- consumer-side wait: waves 0..11 (h/sigp readers) poll barB >= t.
    // barB[Y]=t transitively implies barA>=t, so h(t-1) AND sigp(t-1) are
    // visible. Waves 12-15 read only x -> skip, overlapping x loads.
    if (w < 12 && t > 0) group_wait(barB, l, (unsigned)t);

    // ============ phase A: pre = [h|sigp|x] @ Wcomb ; h = tanh(pre+bias) ============
    f32x4 a00 = {0.f,0.f,0.f,0.f}, a01 = a00, a10 = a00, a11 = a00;
    if (w < 12) {
      // waves 0-7: h (ktg 0..31); waves 8-11: sigp (ktg 32..47) — both w*4+kt.
      // FROZEN R4 pattern: interleaved llc_load8 -> MFMA, one kt at a time.
#pragma unroll
      for (int kt = 0; kt < 4; ++kt) {
        const int ktg = w * 4 + kt;
        f16x8 fa0 = llc_load8(acur + (size_t)ktg * 512 + l * 8);
        f16x8 fa1 = llc_load8(acur + (size_t)(48 + ktg) * 512 + l * 8);
        a00 = MFMA16(fa0, wA[kt][0], a00);
        a01 = MFMA16(fa0, wA[kt][1], a01);
        a10 = MFMA16(fa1, wA[kt][0], a10);
        a11 = MFMA16(fa1, wA[kt][1], a11);
      }
    } else {
      // waves 12-15: x (K 1536..2047, 128 per wave) — plain cached fp32 + cvt
      const int q = w - 12;
      const float* xp0 = xrow0 + (size_t)t * DIN + q * 128 + xco;
      const float* xp1 = xrow1 + (size_t)t * DIN + q * 128 + xco;
#pragma unroll
      for (int kt = 0; kt < 4; ++kt) {
        float4 u0 = *(const float4*)(xp0 + kt * 32);
        float4 u1 = *(const float4*)(xp0 + kt * 32 + 4);
        float4 v0 = *(const float4*)(xp1 + kt * 32);
        float4 v1 = *(const float4*)(xp1 + kt * 32 + 4);
        f16x8 fa0, fa1;
        fa0[0]=(_Float16)u0.x; fa0[1]=(_Float16)u0.y; fa0[2]=(_Float16)u0.z; fa0[3]=(_Float16)u0.w;
        fa0[4]=(_Float16)u1.x; fa0[5]=(_Float16)u1.y; fa0[6]=(_Float16)u1.z; fa0[7]=(_Float16)u1.w;
        fa1[0]=(_Float16)v0.x; fa1[1]=(_Float16)v0.y; fa1[2]=(_Float16)v0.z; fa1[3]=(_Float16)v0.w;
        fa1[4]=(_Float16)v1.x; fa1[5]=(_Float16)v1.y; fa1[6]=(_Float16)v1.z; fa1[7]=(_Float16)v1.w;
        a00 = MFMA16(fa0, wA[kt][0], a00);
        a01 = MFMA16(fa0, wA[kt][1], a01);
        a10 = MFMA16(fa1, wA[kt][0], a10);
        a11 = MFMA16(fa1, wA[kt][1], a11);
      }
    }
    red[w][0][l] = a00; red[w][1][l] = a01; red[w][2][l] = a10; red[w][3][l] = a11;
    __syncthreads();                                     // S1
    if (w < 4) {
      // wave w owns tile (rtA, ctA): reduce 16 K-partials, tanh, stage in LDS
      f32x4 s = red[0][w][l];
#pragma unroll
      for (int j = 1; j < 16; ++j) s += red[j][w][l];
      const int c = ctA * 16 + (l & 15);
#pragma unroll
      for (int i = 0; i < 4; ++i) {
        const int r = rtA * 16 + ((l >> 4) << 2) + i;
        hs[r][c] = (_Float16)tanhf(s[i] + biasv);
      }
    }
    __syncthreads();                                     // S2
    // wave 0 publishes h (128 x 16B units, 2 per lane): store, drain, flag
    if (tid < 64) {
      const int row16 = l & 15, o = (l >> 4) & 3;
      f16x8 t0, t1;
#pragma unroll
      for (int jj = 0; jj < 8; ++jj) {
        t0[jj] = hs[row16][o * 8 + jj];
        t1[jj] = hs[16 + row16][o * 8 + jj];
      }
      const size_t so = (size_t)(((o << 4) | row16) * 8);
      llc_store16(anxt + (size_t)cb * 512 + so, t0);
      llc_store16(anxt + (size_t)(48 + cb) * 512 + so, t1);
      asm volatile("" ::: "memory");
      __builtin_amdgcn_s_waitcnt(0);            // h committed at LLC
      asm volatile("" ::: "memory");
      if (tid == 0)
        __hip_atomic_store(barA + cb, (unsigned)(t + 1),
                           __ATOMIC_RELAXED, __HIP_MEMORY_SCOPE_AGENT);
      asm volatile("" ::: "memory");
    }
    // ALL waves poll h readiness themselves (no barrier handoff)
    group_wait(barA, l, (unsigned)(t + 1));

    // ================= phase B: p = h @ Wp + pb ; sigp = sigmoid(p) =================
    f32x4 b0 = {0.f,0.f,0.f,0.f}, b1 = b0;
#pragma unroll
    for (int kt = 0; kt < 2; ++kt) {
      const int ktg = w * 2 + kt;
      f16x8 h0 = llc_load8(anxt + (size_t)ktg * 512 + l * 8);
      f16x8 h1 = llc_load8(anxt + (size_t)(48 + ktg) * 512 + l * 8);
      b0 = MFMA16(h0, wP[kt], b0);
      b1 = MFMA16(h1, wP[kt], b1);
    }
    red[w][0][l] = b0; red[w][1][l] = b1;
    __syncthreads();                                     // S3
    f32x4 pv = {0.f,0.f,0.f,0.f};
    const bool have_p = (w < 2);
    if (have_p) {
      // wave w owns row-tile w: reduce 16 partials, +pb; sigmoid -> LDS
      f32x4 s = red[0][w][l];
#pragma unroll
      for (int j = 1; j < 16; ++j) s += red[j][w][l];
#pragma unroll
      for (int i = 0; i < 4; ++i) {
        const int grow = w * 16 + ((l >> 4) << 2) + i;
        float p = s[i] + pbv;
        pv[i] = p;
        ps[grow][l & 15] = (_Float16)(1.0f / (1.0f + __expf(-p)));
      }
    }
    __syncthreads();                                     // S4
    // wave 0 publishes sigp (64 x 16B units): store, drain, flag
    if (tid < 64) {
      const int rt = l >> 5, u2 = l & 31;
      const int row16 = u2 & 15, o = u2 >> 4;
      const int kt2 = 32 + (cb >> 1);
      const int oo  = ((cb & 1) << 1) | o;
      f16x8 tp;
#pragma unroll
      for (int jj = 0; jj < 8; ++jj) tp[jj] = ps[rt * 16 + row16][o * 8 + jj];
      llc_store16(anxt + (size_t)(rt * 48 + kt2) * 512 + (size_t)(((oo << 4) | row16) * 8), tp);
      asm volatile("" ::: "memory");
      __builtin_amdgcn_s_waitcnt(0);            // sigp committed at LLC
      asm volatile("" ::: "memory");
      if (tid == 0)
        __hip_atomic_store(barB + cb, (unsigned)(t + 1),
                           __ATOMIC_RELAXED, __HIP_MEMORY_SCOPE_AGENT);
      asm volatile("" ::: "memory");
    }
    // out stores AFTER the flag: never read back, off the drain path
    if (have_p) {
      const int pcol = cb * 16 + (l & 15);
#pragma unroll
      for (int i = 0; i < 4; ++i) {
        const int grow = w * 16 + ((l >> 4) << 2) + i;
        out[((size_t)(g * 32 + grow) * T_ + t) * P_ + pcol] = pv[i];
      }
    }
    // next iteration's loop-top poll (barB >= t+1) is the consumer-side wait
  }
}

extern "C" void kernel_launch(void* const* d_in, const int* in_sizes, int n_in,
                              void* d_out, int out_size, void* d_ws, size_t ws_size,
                              hipStream_t stream)
{
  const float* x    = (const float*)d_in[0];
  const float* krn  = (const float*)d_in[1];
  const float* rk   = (const float*)d_in[2];
  const float* fk   = (const float*)d_in[3];
  const float* pk   = (const float*)d_in[4];
  const float* bias = (const float*)d_in[5];
  const float* pb   = (const float*)d_in[6];
  float* out = (float*)d_out;

  char* ws = (char*)d_ws;
  _Float16* Wpack  = (_Float16*)(ws);
  _Float16* Wppack = (_Float16*)(ws + WPACK_BYTES);
  _Float16* Abuf   = (_Float16*)(ws + WPACK_BYTES + WPPACK_BYTES);
  unsigned* bars   = (unsigned*)(ws + WPACK_BYTES + WPPACK_BYTES + ABUF_BYTES);
  // ws use: 4 MiB + 1 MiB + 1.5 MiB + 2 KiB

  // pack weights, init step-0 activation buffer, zero barriers (every launch:
  // harness re-poisons ws to 0xAA before each timed call)
  hipLaunchKernelGGL(prep_kernel, dim3(11776), dim3(256), 0, stream,
                     krn, rk, fk, pk, Wpack, Wppack, Abuf, bars);

  void* args[] = { (void*)&x, (void*)&bias, (void*)&pb, (void*)&Wpack, (void*)&Wppack,
                   (void*)&Abuf, (void*)&bars, (void*)&out };
  hipLaunchCooperativeKernel((void*)rnn_main, dim3(256), dim3(1024), args, 0, stream);
}